// Round 4
// baseline (1507.817 us; speedup 1.0000x reference)
//
#include <hip/hip_runtime.h>
#include <hip/hip_bf16.h>

#define NU 16384
#define NI 8192
#define TOPK 10
#define NTOT (NU + NI)   // 24576
#define OCAP 64
#define NSEG 4
#define CSEG (NI / NSEG) // 2048
#define NTILES 128       // 8192 / 64
#define NTSEL 12         // tiles rescored per row (10 guaranteed + 2 margin)

typedef short short8v __attribute__((ext_vector_type(8)));
typedef float float4v __attribute__((ext_vector_type(4)));

__device__ __forceinline__ float warp64_sum(float v) {
#pragma unroll
  for (int m = 32; m >= 1; m >>= 1) v += __shfl_xor(v, m);
  return v;
}

// proj = feat @ W + b ; xn = rownorm(proj). Tile: 32 rows x 64 cols (all cols), 256 thr.
__global__ __launch_bounds__(256) void proj_norm_kernel(
    const float* __restrict__ feat, const float* __restrict__ W,
    const float* __restrict__ b, float* __restrict__ xn, int D) {
  __shared__ float sA[64][32];   // [k][r]
  __shared__ float sB[64][68];   // [k][c], padded
  const int tid = threadIdx.x;
  const int r0 = blockIdx.x * 32;
  const int rg = tid >> 4, cg = tid & 15;          // rows rg*2..+1, cols cg*4..+3
  const int rA = tid & 31, kbA = (tid >> 5) * 8;   // A-tile load mapping
  const int kB = tid & 63, cbB = (tid >> 6) * 16;  // B-tile load mapping
  float acc[2][4] = {{0, 0, 0, 0}, {0, 0, 0, 0}};
  for (int kc = 0; kc < D; kc += 64) {
    const float* fp = feat + (size_t)(r0 + rA) * D + kc + kbA;
    float4 p0 = *(const float4*)fp;
    float4 p1 = *(const float4*)(fp + 4);
    sA[kbA + 0][rA] = p0.x; sA[kbA + 1][rA] = p0.y;
    sA[kbA + 2][rA] = p0.z; sA[kbA + 3][rA] = p0.w;
    sA[kbA + 4][rA] = p1.x; sA[kbA + 5][rA] = p1.y;
    sA[kbA + 6][rA] = p1.z; sA[kbA + 7][rA] = p1.w;
    const float* wp = W + (size_t)(kc + kB) * 64 + cbB;
    float4 q0 = *(const float4*)(wp + 0);
    float4 q1 = *(const float4*)(wp + 4);
    float4 q2 = *(const float4*)(wp + 8);
    float4 q3 = *(const float4*)(wp + 12);
    *(float4*)&sB[kB][cbB + 0] = q0;
    *(float4*)&sB[kB][cbB + 4] = q1;
    *(float4*)&sB[kB][cbB + 8] = q2;
    *(float4*)&sB[kB][cbB + 12] = q3;
    __syncthreads();
#pragma unroll 8
    for (int k = 0; k < 64; ++k) {
      float2 a = *(const float2*)&sA[k][rg * 2];
      float4 bv = *(const float4*)&sB[k][cg * 4];
      acc[0][0] += a.x * bv.x; acc[0][1] += a.x * bv.y;
      acc[0][2] += a.x * bv.z; acc[0][3] += a.x * bv.w;
      acc[1][0] += a.y * bv.x; acc[1][1] += a.y * bv.y;
      acc[1][2] += a.y * bv.z; acc[1][3] += a.y * bv.w;
    }
    __syncthreads();
  }
  float4 bb = *(const float4*)(b + cg * 4);
#pragma unroll
  for (int rr = 0; rr < 2; ++rr) {
    float v0 = acc[rr][0] + bb.x, v1 = acc[rr][1] + bb.y;
    float v2 = acc[rr][2] + bb.z, v3 = acc[rr][3] + bb.w;
    float ss = v0 * v0 + v1 * v1 + v2 * v2 + v3 * v3;
#pragma unroll
    for (int m = 8; m >= 1; m >>= 1) ss += __shfl_xor(ss, m);  // 16-lane row group
    float inv = 1.0f / sqrtf(ss);
    float4 o = make_float4(v0 * inv, v1 * inv, v2 * inv, v3 * inv);
    *(float4*)(xn + (size_t)(r0 + rg * 2 + rr) * 64 + cg * 4) = o;
  }
}

// split f32 -> bf16 hi + bf16 lo (x ~= hi + lo), for 3-pass MFMA tilemax
__global__ __launch_bounds__(256) void cvt_split_kernel(
    const float* __restrict__ xn, ushort* __restrict__ hi, ushort* __restrict__ lo) {
  int i = blockIdx.x * blockDim.x + threadIdx.x;
  float4 x = ((const float4*)xn)[i];
  ushort h[4], l[4];
  float xs[4] = {x.x, x.y, x.z, x.w};
#pragma unroll
  for (int j = 0; j < 4; ++j) {
    __hip_bfloat16 hb = __float2bfloat16(xs[j]);
    float hf = __bfloat162float(hb);
    __hip_bfloat16 lb = __float2bfloat16(xs[j] - hf);
    h[j] = *(ushort*)&hb;
    l[j] = *(ushort*)&lb;
  }
  ((ushort4*)hi)[i] = make_ushort4(h[0], h[1], h[2], h[3]);
  ((ushort4*)lo)[i] = make_ushort4(l[0], l[1], l[2], l[3]);
}

// Pass 1: per-(row, 64-col tile) max of sims via MFMA (bf16 hi/lo 3-pass).
// Block: 4 waves x 16 rows = 64 rows; cols = one segment of 2048, staged in LDS.
__global__ __launch_bounds__(256) void sim_tilemax_kernel(
    const ushort* __restrict__ hiV, const ushort* __restrict__ loV,
    const ushort* __restrict__ hiT, const ushort* __restrict__ loT,
    float* __restrict__ tmax) {
  const int m = blockIdx.z;
  const ushort* hi = m ? hiT : hiV;
  const ushort* lo = m ? loT : loV;
  const int seg = blockIdx.y;
  const int c_base = seg * CSEG;
  const int r_base = blockIdx.x * 64;
  __shared__ ushort sH[64][64];
  __shared__ ushort sL[64][64];
  const int tid = threadIdx.x;
  const int wave = tid >> 6, lane = tid & 63;
  const int lr = lane & 15, lg = lane >> 4;
  const int my_row = r_base + wave * 16 + lr;
  // B fragments (this wave's 16 sim-rows), hi/lo x 2 K-chunks
  short8v bh[2], bl[2];
  {
    const ushort* rp = hi + (size_t)my_row * 64 + lg * 8;
    bh[0] = *(const short8v*)(rp);
    bh[1] = *(const short8v*)(rp + 32);
    const ushort* rp2 = lo + (size_t)my_row * 64 + lg * 8;
    bl[0] = *(const short8v*)(rp2);
    bl[1] = *(const short8v*)(rp2 + 32);
  }
  float* tout = tmax + ((size_t)m * NI + my_row) * NTILES + seg * 32;

  // staging map: thread t -> col-row sc = t>>2, 32B chunk sq = (t&3)*32 (row = 128B)
  const int sc = tid >> 2, sq = (tid & 3) * 32;
  const int sw = (sc & 7) << 4;  // XOR swizzle (G4)
  for (int c0 = 0; c0 < CSEG; c0 += 64) {
    __syncthreads();
    const char* gh = (const char*)(hi + (size_t)(c_base + c0 + sc) * 64);
    const char* gl2 = (const char*)(lo + (size_t)(c_base + c0 + sc) * 64);
    *(float4*)((char*)&sH[sc][0] + (sq ^ sw)) = *(const float4*)(gh + sq);
    *(float4*)((char*)&sH[sc][0] + ((sq + 16) ^ sw)) = *(const float4*)(gh + sq + 16);
    *(float4*)((char*)&sL[sc][0] + (sq ^ sw)) = *(const float4*)(gl2 + sq);
    *(float4*)((char*)&sL[sc][0] + ((sq + 16) ^ sw)) = *(const float4*)(gl2 + sq + 16);
    __syncthreads();
    float mx = -3.0e38f;
#pragma unroll
    for (int s = 0; s < 4; ++s) {
      const int ca = s * 16 + lr;          // A-row = local col index
      const int cw = (ca & 7) << 4;
      const int kb0 = (lg * 16) ^ cw;      // K-chunk 0 byte offset
      const int kb1 = (lg * 16 + 64) ^ cw; // K-chunk 1
      short8v ah0 = *(const short8v*)((const char*)&sH[ca][0] + kb0);
      short8v ah1 = *(const short8v*)((const char*)&sH[ca][0] + kb1);
      short8v al0 = *(const short8v*)((const char*)&sL[ca][0] + kb0);
      short8v al1 = *(const short8v*)((const char*)&sL[ca][0] + kb1);
      float4v acc = {0.f, 0.f, 0.f, 0.f};
      acc = __builtin_amdgcn_mfma_f32_16x16x32_bf16(ah0, bh[0], acc, 0, 0, 0);
      acc = __builtin_amdgcn_mfma_f32_16x16x32_bf16(ah1, bh[1], acc, 0, 0, 0);
      acc = __builtin_amdgcn_mfma_f32_16x16x32_bf16(ah0, bl[0], acc, 0, 0, 0);
      acc = __builtin_amdgcn_mfma_f32_16x16x32_bf16(ah1, bl[1], acc, 0, 0, 0);
      acc = __builtin_amdgcn_mfma_f32_16x16x32_bf16(al0, bh[0], acc, 0, 0, 0);
      acc = __builtin_amdgcn_mfma_f32_16x16x32_bf16(al1, bh[1], acc, 0, 0, 0);
      mx = fmaxf(mx, fmaxf(fmaxf(acc[0], acc[1]), fmaxf(acc[2], acc[3])));
    }
    // reduce over the 4 lanes (lg) sharing this row
    mx = fmaxf(mx, __shfl_xor(mx, 16));
    mx = fmaxf(mx, __shfl_xor(mx, 32));
    if (lg == 0) tout[c0 >> 6] = mx;
  }
}

// Pass 2: per row, select top-NTSEL tiles by tilemax, rescore 64*NTSEL cols in
// exact f32, exact top-10 (ties -> lower index). Wave per row.
__global__ __launch_bounds__(256) void tile_rescore_kernel(
    const float* __restrict__ xn_v, const float* __restrict__ xn_t,
    const float* __restrict__ tmax,
    float* __restrict__ tkvV, int* __restrict__ tkiV,
    float* __restrict__ tkvT, int* __restrict__ tkiT) {
  const int task = blockIdx.x * 4 + (threadIdx.x >> 6);  // 0 .. 2*NI-1
  const int lane = threadIdx.x & 63;
  const int m = task >> 13;
  const int row = task & (NI - 1);
  const float* xn = m ? xn_t : xn_v;
  const float* tmr = tmax + ((size_t)m * NI + row) * NTILES;
  float tv0 = tmr[lane], tv1 = tmr[64 + lane];
  int tl[NTSEL];
#pragma unroll
  for (int t = 0; t < NTSEL; ++t) {
    float bv; int bi;
    if (tv0 >= tv1) { bv = tv0; bi = lane; } else { bv = tv1; bi = 64 + lane; }
#pragma unroll
    for (int mm = 1; mm < 64; mm <<= 1) {
      float ov = __shfl_xor(bv, mm);
      int oi = __shfl_xor(bi, mm);
      bool take = (ov > bv) || (ov == bv && oi < bi);
      bv = take ? ov : bv; bi = take ? oi : bi;
    }
    tl[t] = bi;  // uniform across lanes
    if ((bi & 63) == lane) {
      if (bi < 64) tv0 = -3.0e38f; else tv1 = -3.0e38f;
    }
  }
  // row vector into regs
  float4 rv[16];
  const float4* rp = (const float4*)(xn + (size_t)row * 64);
#pragma unroll
  for (int k = 0; k < 16; ++k) rv[k] = rp[k];
  float pv[NTSEL]; int pc[NTSEL];
#pragma unroll
  for (int t = 0; t < NTSEL; ++t) {
    int c = tl[t] * 64 + lane;
    const float4* cp = (const float4*)(xn + (size_t)c * 64);
    float s = 0.0f;
#pragma unroll
    for (int k = 0; k < 16; ++k) {
      float4 bv4 = cp[k];
      s += rv[k].x * bv4.x; s += rv[k].y * bv4.y;
      s += rv[k].z * bv4.z; s += rv[k].w * bv4.w;
    }
    pv[t] = s; pc[t] = c;
  }
  float* tv = m ? tkvT : tkvV;
  int* ti = m ? tkiT : tkiV;
  for (int q = 0; q < TOPK; ++q) {
    // per-lane best of NTSEL slots
    float bv = -3.0e38f; int bc = 0x7fffffff, bs = -1;
#pragma unroll
    for (int t = 0; t < NTSEL; ++t) {
      bool tk = (pv[t] > bv) || (pv[t] == bv && pc[t] < bc);
      bv = tk ? pv[t] : bv; bc = tk ? pc[t] : bc; bs = tk ? t : bs;
    }
    // cross-lane argmax (value desc, index asc)
    float v = bv; int c = bc; int wl = lane;
#pragma unroll
    for (int mm = 1; mm < 64; mm <<= 1) {
      float ov = __shfl_xor(v, mm);
      int oc = __shfl_xor(c, mm);
      int owl = __shfl_xor(wl, mm);
      bool take = (ov > v) || (ov == v && oc < c);
      v = take ? ov : v; c = take ? oc : c; wl = take ? owl : wl;
    }
    if (lane == wl) {
#pragma unroll
      for (int t = 0; t < NTSEL; ++t)
        if (t == bs) pv[t] = -3.0e38f;
    }
    if (lane == 0) { tv[(size_t)row * TOPK + q] = v; ti[(size_t)row * TOPK + q] = c; }
  }
}

// dis[r] for normalized_laplacian(learned): d = w0*sum(topk_v)+w1*sum(topk_t)
__global__ void dis_kernel(const float* __restrict__ tkv_v, const float* __restrict__ tkv_t,
                           const float* __restrict__ iw, float* __restrict__ dis) {
  int r = blockIdx.x * blockDim.x + threadIdx.x;
  if (r >= NI) return;
  float ea = expf(iw[0]), eb = expf(iw[1]);
  float w0 = ea / (ea + eb), w1 = eb / (ea + eb);
  float s0 = 0.f, s1 = 0.f;
  for (int j = 0; j < TOPK; ++j) { s0 += tkv_v[r * TOPK + j]; s1 += tkv_t[r * TOPK + j]; }
  float d = w0 * s0 + w1 * s1;
  dis[r] = (d > 0.0f) ? (1.0f / sqrtf(d)) : 0.0f;
}

// stream Sim_v/Sim_t (10 nz/row) -> compact per-row lists with weight 0.7*w_m*val
__global__ __launch_bounds__(256) void scan_sim_kernel(
    const float* __restrict__ Sv, const float* __restrict__ St,
    const float* __restrict__ iw, int* __restrict__ ocols,
    float* __restrict__ ow, int* __restrict__ ocnt) {
  const int lane = threadIdx.x & 63;
  const int row = blockIdx.x * 4 + (threadIdx.x >> 6);
  float ea = expf(iw[0]), eb = expf(iw[1]);
  float wA = 0.7f * ea / (ea + eb), wB = 0.7f * eb / (ea + eb);
  int cnt = 0;
  int* oc = ocols + (size_t)row * OCAP;
  float* op = ow + (size_t)row * OCAP;
#pragma unroll 1
  for (int m = 0; m < 2; ++m) {
    const float* S = m ? St : Sv;
    float wgt = m ? wB : wA;
    const float4* rp = (const float4*)(S + (size_t)row * NI);
    for (int it = 0; it < NI / 256; ++it) {
      float4 v = rp[it * 64 + lane];
      int cb = it * 256 + lane * 4;
#pragma unroll
      for (int j = 0; j < 4; ++j) {
        float x = (j == 0) ? v.x : (j == 1) ? v.y : (j == 2) ? v.z : v.w;
        bool nz = (x != 0.0f);
        unsigned long long mk = __ballot(nz);
        int pre = __popcll(mk & ((1ull << lane) - 1ull));
        if (nz) {
          int p = cnt + pre;
          if (p < OCAP) { oc[p] = cb + j; op[p] = wgt * x; }
        }
        cnt += __popcll(mk);
      }
    }
  }
  if (lane == 0) ocnt[row] = (cnt < OCAP) ? cnt : OCAP;
}

// item_emb = Si @ Gi (sparse), then nitem = l2_normalize(item_emb)
__global__ __launch_bounds__(256) void item_emb_kernel(
    const float* __restrict__ Gi,
    const float* __restrict__ tkv_v, const int* __restrict__ tki_v,
    const float* __restrict__ tkv_t, const int* __restrict__ tki_t,
    const float* __restrict__ dis, const int* __restrict__ ocols,
    const float* __restrict__ ow, const int* __restrict__ ocnt,
    const float* __restrict__ iw, float* __restrict__ nitem) {
  const int d = threadIdx.x & 63;
  const int row = blockIdx.x * 4 + (threadIdx.x >> 6);
  float ea = expf(iw[0]), eb = expf(iw[1]);
  float w0 = ea / (ea + eb), w1 = eb / (ea + eb);
  float disr = dis[row];
  float acc = 0.0f;
#pragma unroll 1
  for (int m = 0; m < 2; ++m) {
    const float* tv = m ? tkv_t : tkv_v;
    const int* ti = m ? tki_t : tki_v;
    float wm = (m ? w1 : w0) * 0.3f * disr;
    for (int j = 0; j < TOPK; ++j) {
      float val = tv[(size_t)row * TOPK + j];
      int c = ti[(size_t)row * TOPK + j];
      acc += wm * val * dis[c] * Gi[(size_t)c * 64 + d];
    }
  }
  int cn = ocnt[row];
  for (int j = 0; j < cn; ++j) {
    int c = ocols[(size_t)row * OCAP + j];
    float wv = ow[(size_t)row * OCAP + j];
    acc += wv * Gi[(size_t)c * 64 + d];
  }
  float ss = warp64_sum(acc * acc);
  float nr = sqrtf(ss);
  nitem[(size_t)row * 64 + d] = acc / fmaxf(nr, 1e-12f);
}

__global__ void hist_kernel(const int* __restrict__ dst, int* __restrict__ deg, int n) {
  int e = blockIdx.x * blockDim.x + threadIdx.x;
  if (e < n) atomicAdd(&deg[dst[e]], 1);
}

__global__ __launch_bounds__(256) void scan_rowptr_kernel(
    const int* __restrict__ deg, int* __restrict__ row_ptr,
    int* __restrict__ cursor, int n) {
  __shared__ int s[256];
  __shared__ int carry;
  int tid = threadIdx.x;
  if (tid == 0) carry = 0;
  __syncthreads();
  for (int base = 0; base < n; base += 256) {
    int x = deg[base + tid];
    s[tid] = x;
    __syncthreads();
#pragma unroll
    for (int off = 1; off < 256; off <<= 1) {
      int t = (tid >= off) ? s[tid - off] : 0;
      __syncthreads();
      s[tid] += t;
      __syncthreads();
    }
    int incl = s[tid];
    int base_c = carry;
    int excl = base_c + incl - x;
    row_ptr[base + tid] = excl;
    cursor[base + tid] = excl;
    __syncthreads();
    if (tid == 255) carry = base_c + incl;
    __syncthreads();
  }
  if (tid == 0) row_ptr[n] = carry;
}

__global__ void fill_kernel(const int* __restrict__ src, const int* __restrict__ dst,
                            int* __restrict__ cursor, int* __restrict__ csr, int n) {
  int e = blockIdx.x * blockDim.x + threadIdx.x;
  if (e < n) {
    int p = atomicAdd(&cursor[dst[e]], 1);
    csr[p] = src[e];
  }
}

// agg[row] = sum over CSR sources; out = l2_normalize(agg)
__global__ __launch_bounds__(256) void segsum_kernel(
    const float* __restrict__ inU, const float* __restrict__ inI,
    const int* __restrict__ row_ptr, const int* __restrict__ csr,
    float* __restrict__ outp) {
  const int d = threadIdx.x & 63;
  const int row = blockIdx.x * 4 + (threadIdx.x >> 6);
  int a = row_ptr[row], bnd = row_ptr[row + 1];
  float acc = 0.0f;
  for (int e = a; e < bnd; ++e) {
    int s = csr[e];
    const float* sp = (s < NU) ? (inU + (size_t)s * 64) : (inI + (size_t)(s - NU) * 64);
    acc += sp[d];
  }
  float ss = warp64_sum(acc * acc);
  float nr = sqrtf(ss);
  outp[(size_t)row * 64 + d] = acc / fmaxf(nr, 1e-12f);
}

__global__ void final_kernel(const float* __restrict__ Gu, const float* __restrict__ Gi,
                             const float* __restrict__ e1b, const float* __restrict__ e2b,
                             const float* __restrict__ nitem, float* __restrict__ outp) {
  int idx = blockIdx.x * blockDim.x + threadIdx.x;
  int r = idx >> 6, d = idx & 63;
  float v0 = (r < NU) ? Gu[(size_t)r * 64 + d] : Gi[(size_t)(r - NU) * 64 + d];
  float v = (v0 + e1b[idx] + e2b[idx]) * (1.0f / 3.0f);
  if (r >= NU) v += nitem[(size_t)(r - NU) * 64 + d];
  outp[idx] = v;
}

extern "C" void kernel_launch(void* const* d_in, const int* in_sizes, int n_in,
                              void* d_out, int out_size, void* d_ws, size_t ws_size,
                              hipStream_t stream) {
  const float* Gu = (const float*)d_in[0];
  const float* Gi = (const float*)d_in[1];
  const float* feat_v = (const float*)d_in[2];
  const float* feat_t = (const float*)d_in[3];
  const float* W_v = (const float*)d_in[4];
  const float* b_v = (const float*)d_in[5];
  const float* W_t = (const float*)d_in[6];
  const float* b_t = (const float*)d_in[7];
  const float* iw = (const float*)d_in[8];
  const float* Sv = (const float*)d_in[9];
  const float* St = (const float*)d_in[10];
  const int* eidx = (const int*)d_in[11];
  const int twoE = in_sizes[11] / 2;  // 1048576 directed edges
  const int* esrc = eidx;
  const int* edst = eidx + twoE;
  float* outp = (float*)d_out;

  char* w = (char*)d_ws;
  size_t off = 0;
  auto alloc = [&](size_t bytes) -> void* {
    void* p = w + off;
    off = (off + bytes + 255) & ~(size_t)255;
    return p;
  };
  float* xn_v = (float*)alloc((size_t)NI * 64 * 4);
  float* xn_t = (float*)alloc((size_t)NI * 64 * 4);
  ushort* hiV = (ushort*)alloc((size_t)NI * 64 * 2);
  ushort* loV = (ushort*)alloc((size_t)NI * 64 * 2);
  ushort* hiT = (ushort*)alloc((size_t)NI * 64 * 2);
  ushort* loT = (ushort*)alloc((size_t)NI * 64 * 2);
  float* tmax = (float*)alloc((size_t)2 * NI * NTILES * 4);  // 8 MB
  float* tkvV = (float*)alloc((size_t)NI * TOPK * 4);
  int* tkiV = (int*)alloc((size_t)NI * TOPK * 4);
  float* tkvT = (float*)alloc((size_t)NI * TOPK * 4);
  int* tkiT = (int*)alloc((size_t)NI * TOPK * 4);
  float* dis = (float*)alloc((size_t)NI * 4);
  int* ocols = (int*)alloc((size_t)NI * OCAP * 4);
  float* ow = (float*)alloc((size_t)NI * OCAP * 4);
  int* ocnt = (int*)alloc((size_t)NI * 4);
  float* nitem = (float*)alloc((size_t)NI * 64 * 4);
  float* e1b = (float*)alloc((size_t)NTOT * 64 * 4);
  float* e2b = (float*)alloc((size_t)NTOT * 64 * 4);
  int* deg = (int*)alloc((size_t)NTOT * 4);
  int* row_ptr = (int*)alloc((size_t)(NTOT + 1) * 4);
  int* cursor = (int*)alloc((size_t)NTOT * 4);
  int* csr = (int*)alloc((size_t)twoE * 4);
  if (off > ws_size) return;  // ws too small: fail visibly (output stays zero)

  hipMemsetAsync(deg, 0, (size_t)NTOT * 4, stream);

  proj_norm_kernel<<<NI / 32, 256, 0, stream>>>(feat_v, W_v, b_v, xn_v, 4096);
  proj_norm_kernel<<<NI / 32, 256, 0, stream>>>(feat_t, W_t, b_t, xn_t, 384);
  cvt_split_kernel<<<(NI * 64 / 4) / 256, 256, 0, stream>>>(xn_v, hiV, loV);
  cvt_split_kernel<<<(NI * 64 / 4) / 256, 256, 0, stream>>>(xn_t, hiT, loT);
  sim_tilemax_kernel<<<dim3(NI / 64, NSEG, 2), 256, 0, stream>>>(hiV, loV, hiT, loT, tmax);
  tile_rescore_kernel<<<(2 * NI) / 4, 256, 0, stream>>>(xn_v, xn_t, tmax, tkvV, tkiV,
                                                        tkvT, tkiT);
  dis_kernel<<<(NI + 255) / 256, 256, 0, stream>>>(tkvV, tkvT, iw, dis);
  scan_sim_kernel<<<NI / 4, 256, 0, stream>>>(Sv, St, iw, ocols, ow, ocnt);
  item_emb_kernel<<<NI / 4, 256, 0, stream>>>(Gi, tkvV, tkiV, tkvT, tkiT, dis, ocols, ow,
                                              ocnt, iw, nitem);
  hist_kernel<<<(twoE + 255) / 256, 256, 0, stream>>>(edst, deg, twoE);
  scan_rowptr_kernel<<<1, 256, 0, stream>>>(deg, row_ptr, cursor, NTOT);
  fill_kernel<<<(twoE + 255) / 256, 256, 0, stream>>>(esrc, edst, cursor, csr, twoE);
  segsum_kernel<<<NTOT / 4, 256, 0, stream>>>(Gu, Gi, row_ptr, csr, e1b);
  segsum_kernel<<<NTOT / 4, 256, 0, stream>>>(e1b, e1b + (size_t)NU * 64, row_ptr, csr, e2b);
  final_kernel<<<(NTOT * 64) / 256, 256, 0, stream>>>(Gu, Gi, e1b, e2b, nitem, outp);
}

// Round 5
// 928.567 us; speedup vs baseline: 1.6238x; 1.6238x over previous
//
#include <hip/hip_runtime.h>
#include <hip/hip_bf16.h>

#define NU 16384
#define NI 8192
#define TOPK 10
#define NTOT (NU + NI)   // 24576
#define OCAP 64
#define NSEG 4
#define CSEG (NI / NSEG) // 2048
#define NTILES 128       // 8192 / 64
#define NTSEL 12         // tiles rescored per row (10 guaranteed + 2 margin)

typedef short short8v __attribute__((ext_vector_type(8)));
typedef float float4v __attribute__((ext_vector_type(4)));

__device__ __forceinline__ float warp64_sum(float v) {
#pragma unroll
  for (int m = 32; m >= 1; m >>= 1) v += __shfl_xor(v, m);
  return v;
}

// proj = feat @ W + b ; xn = rownorm(proj). Tile: 32 rows x 64 cols (all cols), 256 thr.
__global__ __launch_bounds__(256) void proj_norm_kernel(
    const float* __restrict__ feat, const float* __restrict__ W,
    const float* __restrict__ b, float* __restrict__ xn, int D) {
  __shared__ float sA[64][32];   // [k][r]
  __shared__ float sB[64][68];   // [k][c], padded
  const int tid = threadIdx.x;
  const int r0 = blockIdx.x * 32;
  const int rg = tid >> 4, cg = tid & 15;          // rows rg*2..+1, cols cg*4..+3
  const int rA = tid & 31, kbA = (tid >> 5) * 8;   // A-tile load mapping
  const int kB = tid & 63, cbB = (tid >> 6) * 16;  // B-tile load mapping
  float acc[2][4] = {{0, 0, 0, 0}, {0, 0, 0, 0}};
  for (int kc = 0; kc < D; kc += 64) {
    const float* fp = feat + (size_t)(r0 + rA) * D + kc + kbA;
    float4 p0 = *(const float4*)fp;
    float4 p1 = *(const float4*)(fp + 4);
    sA[kbA + 0][rA] = p0.x; sA[kbA + 1][rA] = p0.y;
    sA[kbA + 2][rA] = p0.z; sA[kbA + 3][rA] = p0.w;
    sA[kbA + 4][rA] = p1.x; sA[kbA + 5][rA] = p1.y;
    sA[kbA + 6][rA] = p1.z; sA[kbA + 7][rA] = p1.w;
    const float* wp = W + (size_t)(kc + kB) * 64 + cbB;
    float4 q0 = *(const float4*)(wp + 0);
    float4 q1 = *(const float4*)(wp + 4);
    float4 q2 = *(const float4*)(wp + 8);
    float4 q3 = *(const float4*)(wp + 12);
    *(float4*)&sB[kB][cbB + 0] = q0;
    *(float4*)&sB[kB][cbB + 4] = q1;
    *(float4*)&sB[kB][cbB + 8] = q2;
    *(float4*)&sB[kB][cbB + 12] = q3;
    __syncthreads();
#pragma unroll 8
    for (int k = 0; k < 64; ++k) {
      float2 a = *(const float2*)&sA[k][rg * 2];
      float4 bv = *(const float4*)&sB[k][cg * 4];
      acc[0][0] += a.x * bv.x; acc[0][1] += a.x * bv.y;
      acc[0][2] += a.x * bv.z; acc[0][3] += a.x * bv.w;
      acc[1][0] += a.y * bv.x; acc[1][1] += a.y * bv.y;
      acc[1][2] += a.y * bv.z; acc[1][3] += a.y * bv.w;
    }
    __syncthreads();
  }
  float4 bb = *(const float4*)(b + cg * 4);
#pragma unroll
  for (int rr = 0; rr < 2; ++rr) {
    float v0 = acc[rr][0] + bb.x, v1 = acc[rr][1] + bb.y;
    float v2 = acc[rr][2] + bb.z, v3 = acc[rr][3] + bb.w;
    float ss = v0 * v0 + v1 * v1 + v2 * v2 + v3 * v3;
#pragma unroll
    for (int m = 8; m >= 1; m >>= 1) ss += __shfl_xor(ss, m);  // 16-lane row group
    float inv = 1.0f / sqrtf(ss);
    float4 o = make_float4(v0 * inv, v1 * inv, v2 * inv, v3 * inv);
    *(float4*)(xn + (size_t)(r0 + rg * 2 + rr) * 64 + cg * 4) = o;
  }
}

// split f32 -> bf16 hi + bf16 lo (x ~= hi + lo), for 3-pass MFMA tilemax
__global__ __launch_bounds__(256) void cvt_split_kernel(
    const float* __restrict__ xn, ushort* __restrict__ hi, ushort* __restrict__ lo) {
  int i = blockIdx.x * blockDim.x + threadIdx.x;
  float4 x = ((const float4*)xn)[i];
  ushort h[4], l[4];
  float xs[4] = {x.x, x.y, x.z, x.w};
#pragma unroll
  for (int j = 0; j < 4; ++j) {
    __hip_bfloat16 hb = __float2bfloat16(xs[j]);
    float hf = __bfloat162float(hb);
    __hip_bfloat16 lb = __float2bfloat16(xs[j] - hf);
    h[j] = *(ushort*)&hb;
    l[j] = *(ushort*)&lb;
  }
  ((ushort4*)hi)[i] = make_ushort4(h[0], h[1], h[2], h[3]);
  ((ushort4*)lo)[i] = make_ushort4(l[0], l[1], l[2], l[3]);
}

// Pass 1: per-(row, 64-col tile) max of sims via MFMA (bf16 hi/lo 3-pass).
// Block: 4 waves x 16 rows = 64 rows; cols = one segment of 2048, staged in LDS.
__global__ __launch_bounds__(256) void sim_tilemax_kernel(
    const ushort* __restrict__ hiV, const ushort* __restrict__ loV,
    const ushort* __restrict__ hiT, const ushort* __restrict__ loT,
    float* __restrict__ tmax) {
  const int m = blockIdx.z;
  const ushort* hi = m ? hiT : hiV;
  const ushort* lo = m ? loT : loV;
  const int seg = blockIdx.y;
  const int c_base = seg * CSEG;
  const int r_base = blockIdx.x * 64;
  __shared__ ushort sH[64][64];
  __shared__ ushort sL[64][64];
  const int tid = threadIdx.x;
  const int wave = tid >> 6, lane = tid & 63;
  const int lr = lane & 15, lg = lane >> 4;
  const int my_row = r_base + wave * 16 + lr;
  // B fragments (this wave's 16 sim-rows), hi/lo x 2 K-chunks
  short8v bh[2], bl[2];
  {
    const ushort* rp = hi + (size_t)my_row * 64 + lg * 8;
    bh[0] = *(const short8v*)(rp);
    bh[1] = *(const short8v*)(rp + 32);
    const ushort* rp2 = lo + (size_t)my_row * 64 + lg * 8;
    bl[0] = *(const short8v*)(rp2);
    bl[1] = *(const short8v*)(rp2 + 32);
  }
  float* tout = tmax + ((size_t)m * NI + my_row) * NTILES + seg * 32;

  // staging map: thread t -> col-row sc = t>>2, 32B chunk sq = (t&3)*32 (row = 128B)
  const int sc = tid >> 2, sq = (tid & 3) * 32;
  const int sw = (sc & 7) << 4;  // XOR swizzle (G4)
  for (int c0 = 0; c0 < CSEG; c0 += 64) {
    __syncthreads();
    const char* gh = (const char*)(hi + (size_t)(c_base + c0 + sc) * 64);
    const char* gl2 = (const char*)(lo + (size_t)(c_base + c0 + sc) * 64);
    *(float4*)((char*)&sH[sc][0] + (sq ^ sw)) = *(const float4*)(gh + sq);
    *(float4*)((char*)&sH[sc][0] + ((sq + 16) ^ sw)) = *(const float4*)(gh + sq + 16);
    *(float4*)((char*)&sL[sc][0] + (sq ^ sw)) = *(const float4*)(gl2 + sq);
    *(float4*)((char*)&sL[sc][0] + ((sq + 16) ^ sw)) = *(const float4*)(gl2 + sq + 16);
    __syncthreads();
    float mx = -3.0e38f;
#pragma unroll
    for (int s = 0; s < 4; ++s) {
      const int ca = s * 16 + lr;          // A-row = local col index
      const int cw = (ca & 7) << 4;
      const int kb0 = (lg * 16) ^ cw;      // K-chunk 0 byte offset
      const int kb1 = (lg * 16 + 64) ^ cw; // K-chunk 1
      short8v ah0 = *(const short8v*)((const char*)&sH[ca][0] + kb0);
      short8v ah1 = *(const short8v*)((const char*)&sH[ca][0] + kb1);
      short8v al0 = *(const short8v*)((const char*)&sL[ca][0] + kb0);
      short8v al1 = *(const short8v*)((const char*)&sL[ca][0] + kb1);
      float4v acc = {0.f, 0.f, 0.f, 0.f};
      acc = __builtin_amdgcn_mfma_f32_16x16x32_bf16(ah0, bh[0], acc, 0, 0, 0);
      acc = __builtin_amdgcn_mfma_f32_16x16x32_bf16(ah1, bh[1], acc, 0, 0, 0);
      acc = __builtin_amdgcn_mfma_f32_16x16x32_bf16(ah0, bl[0], acc, 0, 0, 0);
      acc = __builtin_amdgcn_mfma_f32_16x16x32_bf16(ah1, bl[1], acc, 0, 0, 0);
      acc = __builtin_amdgcn_mfma_f32_16x16x32_bf16(al0, bh[0], acc, 0, 0, 0);
      acc = __builtin_amdgcn_mfma_f32_16x16x32_bf16(al1, bh[1], acc, 0, 0, 0);
      mx = fmaxf(mx, fmaxf(fmaxf(acc[0], acc[1]), fmaxf(acc[2], acc[3])));
    }
    // reduce over the 4 lanes (lg) sharing this row
    mx = fmaxf(mx, __shfl_xor(mx, 16));
    mx = fmaxf(mx, __shfl_xor(mx, 32));
    if (lg == 0) tout[c0 >> 6] = mx;
  }
}

// Pass 2: per row, select top-NTSEL tiles by tilemax, rescore 64*NTSEL cols in
// exact f32 with COALESCED loads (lane = (g=col-subslot, d=dim-quad)), exact top-10.
__global__ __launch_bounds__(256) void tile_rescore_kernel(
    const float* __restrict__ xn_v, const float* __restrict__ xn_t,
    const float* __restrict__ tmax,
    float* __restrict__ tkvV, int* __restrict__ tkiV,
    float* __restrict__ tkvT, int* __restrict__ tkiT) {
  const int task = blockIdx.x * 4 + (threadIdx.x >> 6);  // 0 .. 2*NI-1
  const int lane = threadIdx.x & 63;
  const int m = task >> 13;
  const int row = task & (NI - 1);
  const float* xn = m ? xn_t : xn_v;
  const float* tmr = tmax + ((size_t)m * NI + row) * NTILES;
  float tv0 = tmr[lane], tv1 = tmr[64 + lane];
  int tl[NTSEL];
#pragma unroll
  for (int t = 0; t < NTSEL; ++t) {
    float bv; int bi;
    if (tv0 >= tv1) { bv = tv0; bi = lane; } else { bv = tv1; bi = 64 + lane; }
#pragma unroll
    for (int mm = 1; mm < 64; mm <<= 1) {
      float ov = __shfl_xor(bv, mm);
      int oi = __shfl_xor(bi, mm);
      bool take = (ov > bv) || (ov == bv && oi < bi);
      bv = take ? ov : bv; bi = take ? oi : bi;
    }
    tl[t] = bi;  // uniform across lanes
    if ((bi & 63) == lane) {
      if (bi < 64) tv0 = -3.0e38f; else tv1 = -3.0e38f;
    }
  }
  // lane decomposition: g = candidate sub-slot (4 cols/step), d-quad = (lane&15)*4
  const int g = lane >> 4;
  const int jown = lane & 15;          // which step this lane owns
  const int dq = (lane & 15) * 4;
  const float4 rq = *(const float4*)(xn + (size_t)row * 64 + dq);
  float pv[NTSEL]; int pc[NTSEL];
#pragma unroll
  for (int t = 0; t < NTSEL; ++t) pc[t] = tl[t] * 64 + jown * 4 + g;
  for (int t = 0; t < NTSEL; ++t) {
    const float* tb = xn + (size_t)(tl[t] * 64 + g) * 64 + dq;
    float mine = 0.0f;
#pragma unroll
    for (int jj = 0; jj < 16; ++jj) {
      // wave loads 4 consecutive candidate rows (jj*4+g) x 16 dim-quads = 1KB coalesced
      float4 x4 = *(const float4*)(tb + (size_t)jj * 256);
      float s = rq.x * x4.x + rq.y * x4.y + rq.z * x4.z + rq.w * x4.w;
      s += __shfl_xor(s, 1);
      s += __shfl_xor(s, 2);
      s += __shfl_xor(s, 4);
      s += __shfl_xor(s, 8);           // 16-lane group total for col jj*4+g
      mine = (jj == jown) ? s : mine;
    }
    pv[t] = mine;
  }
  float* tv = m ? tkvT : tkvV;
  int* ti = m ? tkiT : tkiV;
  for (int q = 0; q < TOPK; ++q) {
    // per-lane best of NTSEL slots
    float bv = -3.0e38f; int bc = 0x7fffffff, bs = -1;
#pragma unroll
    for (int t = 0; t < NTSEL; ++t) {
      bool tk = (pv[t] > bv) || (pv[t] == bv && pc[t] < bc);
      bv = tk ? pv[t] : bv; bc = tk ? pc[t] : bc; bs = tk ? t : bs;
    }
    // cross-lane argmax (value desc, index asc)
    float v = bv; int c = bc; int wl = lane;
#pragma unroll
    for (int mm = 1; mm < 64; mm <<= 1) {
      float ov = __shfl_xor(v, mm);
      int oc = __shfl_xor(c, mm);
      int owl = __shfl_xor(wl, mm);
      bool take = (ov > v) || (ov == v && oc < c);
      v = take ? ov : v; c = take ? oc : c; wl = take ? owl : wl;
    }
    if (lane == wl) {
#pragma unroll
      for (int t = 0; t < NTSEL; ++t)
        if (t == bs) pv[t] = -3.0e38f;
    }
    if (lane == 0) { tv[(size_t)row * TOPK + q] = v; ti[(size_t)row * TOPK + q] = c; }
  }
}

// dis[r] for normalized_laplacian(learned): d = w0*sum(topk_v)+w1*sum(topk_t)
__global__ void dis_kernel(const float* __restrict__ tkv_v, const float* __restrict__ tkv_t,
                           const float* __restrict__ iw, float* __restrict__ dis) {
  int r = blockIdx.x * blockDim.x + threadIdx.x;
  if (r >= NI) return;
  float ea = expf(iw[0]), eb = expf(iw[1]);
  float w0 = ea / (ea + eb), w1 = eb / (ea + eb);
  float s0 = 0.f, s1 = 0.f;
  for (int j = 0; j < TOPK; ++j) { s0 += tkv_v[r * TOPK + j]; s1 += tkv_t[r * TOPK + j]; }
  float d = w0 * s0 + w1 * s1;
  dis[r] = (d > 0.0f) ? (1.0f / sqrtf(d)) : 0.0f;
}

// stream Sim_v/Sim_t (10 nz/row) -> compact per-row lists with weight 0.7*w_m*val
__global__ __launch_bounds__(256) void scan_sim_kernel(
    const float* __restrict__ Sv, const float* __restrict__ St,
    const float* __restrict__ iw, int* __restrict__ ocols,
    float* __restrict__ ow, int* __restrict__ ocnt) {
  const int lane = threadIdx.x & 63;
  const int row = blockIdx.x * 4 + (threadIdx.x >> 6);
  float ea = expf(iw[0]), eb = expf(iw[1]);
  float wA = 0.7f * ea / (ea + eb), wB = 0.7f * eb / (ea + eb);
  int cnt = 0;
  int* oc = ocols + (size_t)row * OCAP;
  float* op = ow + (size_t)row * OCAP;
#pragma unroll 1
  for (int m = 0; m < 2; ++m) {
    const float* S = m ? St : Sv;
    float wgt = m ? wB : wA;
    const float4* rp = (const float4*)(S + (size_t)row * NI);
    for (int it = 0; it < NI / 256; ++it) {
      float4 v = rp[it * 64 + lane];
      int cb = it * 256 + lane * 4;
#pragma unroll
      for (int j = 0; j < 4; ++j) {
        float x = (j == 0) ? v.x : (j == 1) ? v.y : (j == 2) ? v.z : v.w;
        bool nz = (x != 0.0f);
        unsigned long long mk = __ballot(nz);
        int pre = __popcll(mk & ((1ull << lane) - 1ull));
        if (nz) {
          int p = cnt + pre;
          if (p < OCAP) { oc[p] = cb + j; op[p] = wgt * x; }
        }
        cnt += __popcll(mk);
      }
    }
  }
  if (lane == 0) ocnt[row] = (cnt < OCAP) ? cnt : OCAP;
}

// item_emb = Si @ Gi (sparse), then nitem = l2_normalize(item_emb)
__global__ __launch_bounds__(256) void item_emb_kernel(
    const float* __restrict__ Gi,
    const float* __restrict__ tkv_v, const int* __restrict__ tki_v,
    const float* __restrict__ tkv_t, const int* __restrict__ tki_t,
    const float* __restrict__ dis, const int* __restrict__ ocols,
    const float* __restrict__ ow, const int* __restrict__ ocnt,
    const float* __restrict__ iw, float* __restrict__ nitem) {
  const int d = threadIdx.x & 63;
  const int row = blockIdx.x * 4 + (threadIdx.x >> 6);
  float ea = expf(iw[0]), eb = expf(iw[1]);
  float w0 = ea / (ea + eb), w1 = eb / (ea + eb);
  float disr = dis[row];
  float acc = 0.0f;
#pragma unroll 1
  for (int m = 0; m < 2; ++m) {
    const float* tv = m ? tkv_t : tkv_v;
    const int* ti = m ? tki_t : tki_v;
    float wm = (m ? w1 : w0) * 0.3f * disr;
    for (int j = 0; j < TOPK; ++j) {
      float val = tv[(size_t)row * TOPK + j];
      int c = ti[(size_t)row * TOPK + j];
      acc += wm * val * dis[c] * Gi[(size_t)c * 64 + d];
    }
  }
  int cn = ocnt[row];
  for (int j = 0; j < cn; ++j) {
    int c = ocols[(size_t)row * OCAP + j];
    float wv = ow[(size_t)row * OCAP + j];
    acc += wv * Gi[(size_t)c * 64 + d];
  }
  float ss = warp64_sum(acc * acc);
  float nr = sqrtf(ss);
  nitem[(size_t)row * 64 + d] = acc / fmaxf(nr, 1e-12f);
}

__global__ void hist_kernel(const int* __restrict__ dst, int* __restrict__ deg, int n) {
  int e = blockIdx.x * blockDim.x + threadIdx.x;
  if (e < n) atomicAdd(&deg[dst[e]], 1);
}

__global__ __launch_bounds__(256) void scan_rowptr_kernel(
    const int* __restrict__ deg, int* __restrict__ row_ptr,
    int* __restrict__ cursor, int n) {
  __shared__ int s[256];
  __shared__ int carry;
  int tid = threadIdx.x;
  if (tid == 0) carry = 0;
  __syncthreads();
  for (int base = 0; base < n; base += 256) {
    int x = deg[base + tid];
    s[tid] = x;
    __syncthreads();
#pragma unroll
    for (int off = 1; off < 256; off <<= 1) {
      int t = (tid >= off) ? s[tid - off] : 0;
      __syncthreads();
      s[tid] += t;
      __syncthreads();
    }
    int incl = s[tid];
    int base_c = carry;
    int excl = base_c + incl - x;
    row_ptr[base + tid] = excl;
    cursor[base + tid] = excl;
    __syncthreads();
    if (tid == 255) carry = base_c + incl;
    __syncthreads();
  }
  if (tid == 0) row_ptr[n] = carry;
}

__global__ void fill_kernel(const int* __restrict__ src, const int* __restrict__ dst,
                            int* __restrict__ cursor, int* __restrict__ csr, int n) {
  int e = blockIdx.x * blockDim.x + threadIdx.x;
  if (e < n) {
    int p = atomicAdd(&cursor[dst[e]], 1);
    csr[p] = src[e];
  }
}

// agg[row] = sum over CSR sources; out = l2_normalize(agg)
__global__ __launch_bounds__(256) void segsum_kernel(
    const float* __restrict__ inU, const float* __restrict__ inI,
    const int* __restrict__ row_ptr, const int* __restrict__ csr,
    float* __restrict__ outp) {
  const int d = threadIdx.x & 63;
  const int row = blockIdx.x * 4 + (threadIdx.x >> 6);
  int a = row_ptr[row], bnd = row_ptr[row + 1];
  float acc = 0.0f;
  for (int e = a; e < bnd; ++e) {
    int s = csr[e];
    const float* sp = (s < NU) ? (inU + (size_t)s * 64) : (inI + (size_t)(s - NU) * 64);
    acc += sp[d];
  }
  float ss = warp64_sum(acc * acc);
  float nr = sqrtf(ss);
  outp[(size_t)row * 64 + d] = acc / fmaxf(nr, 1e-12f);
}

__global__ void final_kernel(const float* __restrict__ Gu, const float* __restrict__ Gi,
                             const float* __restrict__ e1b, const float* __restrict__ e2b,
                             const float* __restrict__ nitem, float* __restrict__ outp) {
  int idx = blockIdx.x * blockDim.x + threadIdx.x;
  int r = idx >> 6, d = idx & 63;
  float v0 = (r < NU) ? Gu[(size_t)r * 64 + d] : Gi[(size_t)(r - NU) * 64 + d];
  float v = (v0 + e1b[idx] + e2b[idx]) * (1.0f / 3.0f);
  if (r >= NU) v += nitem[(size_t)(r - NU) * 64 + d];
  outp[idx] = v;
}

extern "C" void kernel_launch(void* const* d_in, const int* in_sizes, int n_in,
                              void* d_out, int out_size, void* d_ws, size_t ws_size,
                              hipStream_t stream) {
  const float* Gu = (const float*)d_in[0];
  const float* Gi = (const float*)d_in[1];
  const float* feat_v = (const float*)d_in[2];
  const float* feat_t = (const float*)d_in[3];
  const float* W_v = (const float*)d_in[4];
  const float* b_v = (const float*)d_in[5];
  const float* W_t = (const float*)d_in[6];
  const float* b_t = (const float*)d_in[7];
  const float* iw = (const float*)d_in[8];
  const float* Sv = (const float*)d_in[9];
  const float* St = (const float*)d_in[10];
  const int* eidx = (const int*)d_in[11];
  const int twoE = in_sizes[11] / 2;  // 1048576 directed edges
  const int* esrc = eidx;
  const int* edst = eidx + twoE;
  float* outp = (float*)d_out;

  char* w = (char*)d_ws;
  size_t off = 0;
  auto alloc = [&](size_t bytes) -> void* {
    void* p = w + off;
    off = (off + bytes + 255) & ~(size_t)255;
    return p;
  };
  float* xn_v = (float*)alloc((size_t)NI * 64 * 4);
  float* xn_t = (float*)alloc((size_t)NI * 64 * 4);
  ushort* hiV = (ushort*)alloc((size_t)NI * 64 * 2);
  ushort* loV = (ushort*)alloc((size_t)NI * 64 * 2);
  ushort* hiT = (ushort*)alloc((size_t)NI * 64 * 2);
  ushort* loT = (ushort*)alloc((size_t)NI * 64 * 2);
  float* tmax = (float*)alloc((size_t)2 * NI * NTILES * 4);  // 8 MB
  float* tkvV = (float*)alloc((size_t)NI * TOPK * 4);
  int* tkiV = (int*)alloc((size_t)NI * TOPK * 4);
  float* tkvT = (float*)alloc((size_t)NI * TOPK * 4);
  int* tkiT = (int*)alloc((size_t)NI * TOPK * 4);
  float* dis = (float*)alloc((size_t)NI * 4);
  int* ocols = (int*)alloc((size_t)NI * OCAP * 4);
  float* ow = (float*)alloc((size_t)NI * OCAP * 4);
  int* ocnt = (int*)alloc((size_t)NI * 4);
  float* nitem = (float*)alloc((size_t)NI * 64 * 4);
  float* e1b = (float*)alloc((size_t)NTOT * 64 * 4);
  float* e2b = (float*)alloc((size_t)NTOT * 64 * 4);
  int* deg = (int*)alloc((size_t)NTOT * 4);
  int* row_ptr = (int*)alloc((size_t)(NTOT + 1) * 4);
  int* cursor = (int*)alloc((size_t)NTOT * 4);
  int* csr = (int*)alloc((size_t)twoE * 4);
  if (off > ws_size) return;  // ws too small: fail visibly (output stays zero)

  hipMemsetAsync(deg, 0, (size_t)NTOT * 4, stream);

  proj_norm_kernel<<<NI / 32, 256, 0, stream>>>(feat_v, W_v, b_v, xn_v, 4096);
  proj_norm_kernel<<<NI / 32, 256, 0, stream>>>(feat_t, W_t, b_t, xn_t, 384);
  cvt_split_kernel<<<(NI * 64 / 4) / 256, 256, 0, stream>>>(xn_v, hiV, loV);
  cvt_split_kernel<<<(NI * 64 / 4) / 256, 256, 0, stream>>>(xn_t, hiT, loT);
  sim_tilemax_kernel<<<dim3(NI / 64, NSEG, 2), 256, 0, stream>>>(hiV, loV, hiT, loT, tmax);
  tile_rescore_kernel<<<(2 * NI) / 4, 256, 0, stream>>>(xn_v, xn_t, tmax, tkvV, tkiV,
                                                        tkvT, tkiT);
  dis_kernel<<<(NI + 255) / 256, 256, 0, stream>>>(tkvV, tkvT, iw, dis);
  scan_sim_kernel<<<NI / 4, 256, 0, stream>>>(Sv, St, iw, ocols, ow, ocnt);
  item_emb_kernel<<<NI / 4, 256, 0, stream>>>(Gi, tkvV, tkiV, tkvT, tkiT, dis, ocols, ow,
                                              ocnt, iw, nitem);
  hist_kernel<<<(twoE + 255) / 256, 256, 0, stream>>>(edst, deg, twoE);
  scan_rowptr_kernel<<<1, 256, 0, stream>>>(deg, row_ptr, cursor, NTOT);
  fill_kernel<<<(twoE + 255) / 256, 256, 0, stream>>>(esrc, edst, cursor, csr, twoE);
  segsum_kernel<<<NTOT / 4, 256, 0, stream>>>(Gu, Gi, row_ptr, csr, e1b);
  segsum_kernel<<<NTOT / 4, 256, 0, stream>>>(e1b, e1b + (size_t)NU * 64, row_ptr, csr, e2b);
  final_kernel<<<(NTOT * 64) / 256, 256, 0, stream>>>(Gu, Gi, e1b, e2b, nitem, outp);
}